// Round 3
// baseline (497.793 us; speedup 1.0000x reference)
//
#include <hip/hip_runtime.h>

#define LAMBDA_COORD 5.0f
#define LAMBDA_NOOBJ 0.5f

__global__ void zero_out_kernel(float* out) { out[0] = 0.0f; }

// Loss for one cell: p, t point at 30 consecutive floats held in registers
// (constant-index access into SROA'd float4 arrays).
__device__ __forceinline__ float cell_loss(const float* __restrict__ p,
                                           const float* __restrict__ t) {
    float obj   = (t[4] > 0.0f)  ? 1.0f : 0.0f;
    float noobj = (t[4] == 0.0f) ? 1.0f : 0.0f;

    // IoU of both pred boxes vs target box; divide only feeds a compare.
    float ltx0 = fmaxf(p[0], t[0]), lty0 = fmaxf(p[1], t[1]);
    float rbx0 = fminf(p[2], t[2]), rby0 = fminf(p[3], t[3]);
    float inter0 = fmaxf(rbx0 - ltx0, 0.0f) * fmaxf(rby0 - lty0, 0.0f);
    float a10 = (p[2] - p[0]) * (p[3] - p[1]);

    float ltx1 = fmaxf(p[5], t[0]), lty1 = fmaxf(p[6], t[1]);
    float rbx1 = fminf(p[7], t[2]), rby1 = fminf(p[8], t[3]);
    float inter1 = fmaxf(rbx1 - ltx1, 0.0f) * fmaxf(rby1 - lty1, 0.0f);
    float a11 = (p[7] - p[5]) * (p[8] - p[6]);

    float a2 = (t[2] - t[0]) * (t[3] - t[1]);
    float iou0 = __fdividef(inter0, a10 + a2 - inter0);
    float iou1 = __fdividef(inter1, a11 + a2 - inter1);
    bool c0 = (iou0 >= iou1);   // jnp.argmax ties -> box 0

    int o = c0 ? 0 : 5;
    float dx = p[o + 0] - t[o + 0];
    float dy = p[o + 1] - t[o + 1];
    float l1 = dx * dx + dy * dy;
    float sw = sqrtf(p[o + 2]) - sqrtf(t[o + 2]);
    float sh = sqrtf(p[o + 3]) - sqrtf(t[o + 3]);
    float l2 = sw * sw + sh * sh;
    float dc = p[o + 4] - t[o + 4];
    float conf = dc * dc;

    float cls = 0.0f;
#pragma unroll
    for (int c = 10; c < 30; ++c) {
        float d = p[c] - t[c];
        cls += d * d;
    }

    return LAMBDA_COORD * (l1 + l2) * obj
         + conf * obj
         + LAMBDA_NOOBJ * conf * noobj
         + cls * obj;
}

// One thread per CELL PAIR: 2 cells = 60 floats = 240 B = 15 aligned float4s
// per array. 30 independent dwordx4 loads per thread -> 16 B per lane-request
// (max width) and deep MLP. launch_bounds(256,2) caps at 2 waves/EU so the
// compiler can keep all 30 loads hoisted (~120 staging VGPRs) without
// interleaving loads with uses.
__global__ __launch_bounds__(256, 2) void yolo_loss_kernel(
    const float* __restrict__ pred,
    const float* __restrict__ targ,
    float* __restrict__ out,
    int npairs)
{
    int pair = blockIdx.x * blockDim.x + threadIdx.x;
    float loss = 0.0f;

    if (pair < npairs) {
        const float4* p4 = (const float4*)pred + (size_t)pair * 15;
        const float4* t4 = (const float4*)targ + (size_t)pair * 15;

        float4 pv[15], tv[15];
#pragma unroll
        for (int k = 0; k < 15; ++k) pv[k] = p4[k];
#pragma unroll
        for (int k = 0; k < 15; ++k) tv[k] = t4[k];

        const float* P = (const float*)pv;
        const float* T = (const float*)tv;

        loss = cell_loss(P, T) + cell_loss(P + 30, T + 30);
    }

    // Wave-64 butterfly reduction, then cross-wave via LDS, one atomic/block.
#pragma unroll
    for (int off = 32; off > 0; off >>= 1)
        loss += __shfl_down(loss, off, 64);

    __shared__ float wsum[4];
    int lane = threadIdx.x & 63;
    int wid  = threadIdx.x >> 6;
    if (lane == 0) wsum[wid] = loss;
    __syncthreads();
    if (threadIdx.x == 0) {
        atomicAdd(out, wsum[0] + wsum[1] + wsum[2] + wsum[3]);
    }
}

extern "C" void kernel_launch(void* const* d_in, const int* in_sizes, int n_in,
                              void* d_out, int out_size, void* d_ws, size_t ws_size,
                              hipStream_t stream) {
    const float* pred = (const float*)d_in[0];
    const float* targ = (const float*)d_in[1];
    float* out = (float*)d_out;

    int npairs = in_sizes[0] / 60;          // 802,816 (exact)
    int grid = (npairs + 255) / 256;        // 3136

    zero_out_kernel<<<1, 1, 0, stream>>>(out);
    yolo_loss_kernel<<<grid, 256, 0, stream>>>(pred, targ, out, npairs);
}

// Round 4
// 383.245 us; speedup vs baseline: 1.2989x; 1.2989x over previous
//
#include <hip/hip_runtime.h>

#define LAMBDA_COORD 5.0f
#define LAMBDA_NOOBJ 0.5f

__global__ void zero_out_kernel(float* out) { out[0] = 0.0f; }

// Loss for one cell. p/t are constant-index views into SROA'd register
// arrays. NO dynamic indexing anywhere (dynamic idx -> scratch spill, R3).
__device__ __forceinline__ float cell_loss(const float* __restrict__ p,
                                           const float* __restrict__ t) {
    float obj   = (t[4] > 0.0f)  ? 1.0f : 0.0f;
    float noobj = (t[4] == 0.0f) ? 1.0f : 0.0f;

    // IoU of both pred boxes vs target box; divide only feeds a compare.
    float ltx0 = fmaxf(p[0], t[0]), lty0 = fmaxf(p[1], t[1]);
    float rbx0 = fminf(p[2], t[2]), rby0 = fminf(p[3], t[3]);
    float inter0 = fmaxf(rbx0 - ltx0, 0.0f) * fmaxf(rby0 - lty0, 0.0f);
    float a10 = (p[2] - p[0]) * (p[3] - p[1]);

    float ltx1 = fmaxf(p[5], t[0]), lty1 = fmaxf(p[6], t[1]);
    float rbx1 = fminf(p[7], t[2]), rby1 = fminf(p[8], t[3]);
    float inter1 = fmaxf(rbx1 - ltx1, 0.0f) * fmaxf(rby1 - lty1, 0.0f);
    float a11 = (p[7] - p[5]) * (p[8] - p[6]);

    float a2 = (t[2] - t[0]) * (t[3] - t[1]);
    float iou0 = __fdividef(inter0, a10 + a2 - inter0);
    float iou1 = __fdividef(inter1, a11 + a2 - inter1);
    bool c0 = (iou0 >= iou1);   // jnp.argmax ties -> box 0

    // Select chosen-box operands with constant-index ternaries (v_cndmask),
    // keeping every array subscript a literal constant.
    float px = c0 ? p[0] : p[5];
    float py = c0 ? p[1] : p[6];
    float pw = c0 ? p[2] : p[7];
    float ph = c0 ? p[3] : p[8];
    float pc = c0 ? p[4] : p[9];
    float tx = c0 ? t[0] : t[5];
    float ty = c0 ? t[1] : t[6];
    float tw = c0 ? t[2] : t[7];
    float th = c0 ? t[3] : t[8];
    float tc = c0 ? t[4] : t[9];

    float dx = px - tx, dy = py - ty;
    float l1 = dx * dx + dy * dy;
    float sw = sqrtf(pw) - sqrtf(tw);
    float sh = sqrtf(ph) - sqrtf(th);
    float l2 = sw * sw + sh * sh;
    float dc = pc - tc;
    float conf = dc * dc;

    float cls = 0.0f;
#pragma unroll
    for (int c = 10; c < 30; ++c) {
        float d = p[c] - t[c];
        cls += d * d;
    }

    return LAMBDA_COORD * (l1 + l2) * obj
         + conf * obj
         + LAMBDA_NOOBJ * conf * noobj
         + cls * obj;
}

// One thread per CELL PAIR: 2 cells = 60 floats = 240 B = 15 aligned float4s
// per array -> 30 independent dwordx4 loads, 16 B per lane-request, deep MLP.
// launch_bounds(256,2): 2 waves/EU so ~120 staging VGPRs fit without the
// compiler interleaving loads with uses.
__global__ __launch_bounds__(256, 2) void yolo_loss_kernel(
    const float* __restrict__ pred,
    const float* __restrict__ targ,
    float* __restrict__ out,
    int npairs)
{
    int pair = blockIdx.x * blockDim.x + threadIdx.x;
    float loss = 0.0f;

    if (pair < npairs) {
        const float4* p4 = (const float4*)pred + (size_t)pair * 15;
        const float4* t4 = (const float4*)targ + (size_t)pair * 15;

        float4 pv[15], tv[15];
#pragma unroll
        for (int k = 0; k < 15; ++k) pv[k] = p4[k];
#pragma unroll
        for (int k = 0; k < 15; ++k) tv[k] = t4[k];

        const float* P = (const float*)pv;
        const float* T = (const float*)tv;

        loss = cell_loss(P, T) + cell_loss(P + 30, T + 30);
    }

    // Wave-64 butterfly reduction, then cross-wave via LDS, one atomic/block.
#pragma unroll
    for (int off = 32; off > 0; off >>= 1)
        loss += __shfl_down(loss, off, 64);

    __shared__ float wsum[4];
    int lane = threadIdx.x & 63;
    int wid  = threadIdx.x >> 6;
    if (lane == 0) wsum[wid] = loss;
    __syncthreads();
    if (threadIdx.x == 0) {
        atomicAdd(out, wsum[0] + wsum[1] + wsum[2] + wsum[3]);
    }
}

extern "C" void kernel_launch(void* const* d_in, const int* in_sizes, int n_in,
                              void* d_out, int out_size, void* d_ws, size_t ws_size,
                              hipStream_t stream) {
    const float* pred = (const float*)d_in[0];
    const float* targ = (const float*)d_in[1];
    float* out = (float*)d_out;

    int npairs = in_sizes[0] / 60;          // 802,816 (exact)
    int grid = (npairs + 255) / 256;        // 3136

    zero_out_kernel<<<1, 1, 0, stream>>>(out);
    yolo_loss_kernel<<<grid, 256, 0, stream>>>(pred, targ, out, npairs);
}